// Round 18
// baseline (225.693 us; speedup 1.0000x reference)
//
#include <hip/hip_runtime.h>

#define G_N    32
#define MUL    128
#define RADII  20
#define CH     4
#define RES_B  180
#define RES_A  359
#define IDIM   36
#define COEFF_N (G_N*CH*RADII*IDIM)   // 92160 = 360*256
#define NCHUNK 5
#define BCH_BLK 36                    // betas per block (4 waves)
#define BCH_W   9                     // betas per wave
#define PER_G   (RADII*RES_B*RES_A)   // 1292400
#define TOT_L   (G_N*PER_G)           // 41356800 logits
#define TMP_T   (G_N*RADII*RES_B)     // 115200 rows of [12][4] floats

typedef float v2f __attribute__((ext_vector_type(2)));

__device__ __forceinline__ float fexp2(float x){
#if __has_builtin(__builtin_amdgcn_exp2f)
  return __builtin_amdgcn_exp2f(x);
#else
  return exp2f(x);
#endif
}
__device__ __forceinline__ float flog2(float x){
#if __has_builtin(__builtin_amdgcn_logf)
  return __builtin_amdgcn_logf(x);
#else
  return log2f(x);
#endif
}
__device__ __forceinline__ unsigned enc_f(float f){
  unsigned u = __float_as_uint(f);
  return (u & 0x80000000u) ? ~u : (u | 0x80000000u);
}
__device__ __forceinline__ float dec_f(unsigned k){
  return __uint_as_float((k & 0x80000000u) ? (k ^ 0x80000000u) : ~k);
}

__global__ __launch_bounds__(256) void fused_prep_kernel(
                              const float* __restrict__ focus, const float* __restrict__ embt,
                              const float* __restrict__ W, const int* __restrict__ tspec,
                              float* __restrict__ out,
                              float* __restrict__ PYs, float* __restrict__ Ftab){
  __shared__ double ak[RES_B + 1], bk[RES_B + 1];
  int blk = blockIdx.x;
  int t   = threadIdx.x;
  if (blk == 360){
    const double PI = 3.14159265358979323846;
    const double LOG2E = 1.4426950408889634074;
    if (t >= 2 && t <= RES_B){
      ak[t] = (2.0*t - 1.0) / (double)t;
      bk[t] = (t - 1.0) / (double)t;
    }
    __syncthreads();
    if (t < RES_B){
      int i = RES_B - 1 - t;
      double x = cos(PI * (i + 0.75) / (RES_B + 0.5));
      for (int it = 0; it < 3; ++it){
        double p0 = 1.0, p1 = x;
        for (int k = 2; k <= RES_B; ++k){
          double t1 = ak[k] * x;
          double pk = fma(t1, p1, -(bk[k] * p0));
          p0 = p1; p1 = pk;
        }
        x -= p1 * (x*x - 1.0) / ((double)RES_B * (x*p1 - p0));
      }
      double y = x;
      double sy = sqrt(fmax(1.0 - y*y, 0.0));
      double P[6][6];
      P[0][0] = 1.0;
      for (int m = 1; m < 6; ++m) P[m][m] = (2.0*m - 1.0)*sy*P[m-1][m-1];
      for (int m = 0; m < 5; ++m) P[m+1][m] = (2.0*m + 1.0)*y*P[m][m];
      for (int m = 0; m < 6; ++m)
        for (int l = m + 2; l < 6; ++l)
          P[l][m] = ((2.0*l - 1.0)*y*P[l-1][m] - (l + m - 1.0)*P[l-2][m]) / (double)(l - m);
      const double fact[11] = {1,1,2,6,24,120,720,5040,40320,362880,3628800};
      for (int l = 0; l < 6; ++l)
        for (int m = 0; m <= l; ++m){
          double K = sqrt((2.0*l + 1.0)/(4.0*PI)*fact[l-m]/fact[l+m]);
          double v = K * P[l][m] * LOG2E;
          if (m > 0) v *= sqrt(2.0);
          PYs[t*36 + l*6 + m] = (float)v;
        }
    }
    for (int a = t; a < RES_A; a += 256){
      double al = 2.0*PI*a/(double)RES_A;
      Ftab[a*12 + 0] = 1.0f;
      for (int m = 1; m <= 5; ++m){
        Ftab[a*12 + m]     = (float)cos(m*al);
        Ftab[a*12 + 5 + m] = (float)sin(m*al);
      }
      Ftab[a*12 + 11] = 0.f;
    }
  } else {
    int idx = blk * 256 + t;
    int i36 = idx % IDIM;
    int go  = idx / IDIM;
    int o   = go % (CH*RADII);
    int g   = go / (CH*RADII);
    int l   = (int)sqrtf((float)i36 + 0.5f);
    int mo  = i36 - l*l;
    int dim = 2*l + 1;
    const float* fp = focus + g*(MUL*IDIM) + MUL*l*l + mo;
    const float* ep = embt + tspec[g]*(MUL*6) + MUL*l;
    const float* wp = W + l*(MUL*80) + o;
    float s = 0.f;
    #pragma unroll 4
    for (int i = 0; i < MUL; ++i)
      s = fmaf(fp[i*dim] * ep[i], wp[i*80], s);
    out[idx] = s * 0.088388347648318447f;  // 1/sqrt(128)
  }
}

// Hoisted phase-1: one thread per (t=gr*180+beta, mm), all 4 channels ->
// one coalesced float4 store into the padded [TMP_T][12][4] layout.
__global__ __launch_bounds__(256) void tmp_kernel(const float* __restrict__ coeffs,
                                                  const float* __restrict__ PYs,
                                                  float* __restrict__ tmpg){
  int idx  = blockIdx.x * 256 + threadIdx.x;   // < TMP_T*11 exactly
  int mm   = idx % 11;
  int t    = idx / 11;
  int beta = t % RES_B;
  int gr   = t / RES_B;
  int g = gr / RADII, r = gr % RADII;
  int am, ii;
  if (mm == 0)      { am = 0;      ii = 0;        }
  else if (mm <= 5) { am = mm;     ii = mm;       }
  else              { am = mm - 5; ii = -(mm-5);  }
  const float* py  = PYs + beta*36 + am;
  const float* cvp = coeffs + (size_t)(g*CH*RADII + r)*IDIM;   // channel 0
  float s0 = 0.f, s1 = 0.f, s2 = 0.f, s3 = 0.f;
  for (int l = am; l < 6; ++l){
    float p = py[l*6];
    int o = l*l + l + ii;
    s0 = fmaf(cvp[o],                p, s0);
    s1 = fmaf(cvp[RADII*IDIM + o],   p, s1);
    s2 = fmaf(cvp[2*RADII*IDIM + o], p, s2);
    s3 = fmaf(cvp[3*RADII*IDIM + o], p, s3);
  }
  float4 v = {s0, s1, s2, s3};
  reinterpret_cast<float4*>(tmpg)[t*12 + mm] = v;
}

// SGPR-operand compute: the 44 wave-uniform tmp floats per beta are fetched
// through a readfirstlane-forced scalar pointer -> merged s_load_dwordx16
// (one SMEM round broadcasts to all 64 lanes; no LDS traffic at all).
// k-major loop keeps VGPRs ~45 (f[10] + 8 accums): under the 64-VGPR wall.
// Stores h = log2(sum_c 2^h_c) as fp16; per-graph max via atomicMax.
__global__ __launch_bounds__(256, 4) void compute_sgpr_kernel(
                          const float* __restrict__ tmpg, const float* __restrict__ Ftab,
                          _Float16* __restrict__ hbuf, unsigned* __restrict__ gmax){
  int blk   = blockIdx.x;
  int chunk = blk % NCHUNK;
  int gr    = blk / NCHUNK;
  int g = gr / RADII;
  int tid  = threadIdx.x;
  int wave = tid >> 6, lane = tid & 63;
  int b0   = chunk * BCH_BLK + wave * BCH_W;

  __shared__ float wred[4];

  const float* tb = tmpg + ((size_t)gr*RES_B + b0)*48;
  {
    uintptr_t p = (uintptr_t)tb;
    unsigned lo = __builtin_amdgcn_readfirstlane((unsigned)p);
    unsigned hi = __builtin_amdgcn_readfirstlane((unsigned)(p >> 32));
    tb = (const float*)(((uintptr_t)hi << 32) | lo);
  }

  float smx = -1e30f;
  size_t base = ((size_t)gr*RES_B + b0)*RES_A;

  #pragma unroll 1
  for (int k = 0; k < 3; ++k){
    int a = lane + 64*k;                       // alpha-pair index, < 192 <= 358
    const float4* Fq = reinterpret_cast<const float4*>(Ftab);
    float4 fa = Fq[a*3], fb = Fq[a*3+1], fc = Fq[a*3+2];
    float f1v=fa.y, f2v=fa.z, f3v=fa.w, f4v=fb.x, f5v=fb.y;
    float f6v=fb.z, f7v=fb.w, f8v=fc.x, f9v=fc.y, f10v=fc.z;
    bool ok = (k < 2) || (lane < 52);
    size_t ro = base;
    #pragma unroll 1
    for (int bl = 0; bl < BCH_W; ++bl){
      const float4* tq = reinterpret_cast<const float4*>(tb + bl*48);
      float4 q0 = tq[0], q1 = tq[1], q2 = tq[2], q3 = tq[3], q4 = tq[4];
      float4 q5 = tq[5], q6 = tq[6], q7 = tq[7], q8 = tq[8], q9 = tq[9], q10 = tq[10];
      float C0 = q0.x, C1 = q0.y, C2 = q0.z, C3 = q0.w;
      C0 = fmaf(q1.x, f1v, C0); C1 = fmaf(q1.y, f1v, C1); C2 = fmaf(q1.z, f1v, C2); C3 = fmaf(q1.w, f1v, C3);
      C0 = fmaf(q2.x, f2v, C0); C1 = fmaf(q2.y, f2v, C1); C2 = fmaf(q2.z, f2v, C2); C3 = fmaf(q2.w, f2v, C3);
      C0 = fmaf(q3.x, f3v, C0); C1 = fmaf(q3.y, f3v, C1); C2 = fmaf(q3.z, f3v, C2); C3 = fmaf(q3.w, f3v, C3);
      C0 = fmaf(q4.x, f4v, C0); C1 = fmaf(q4.y, f4v, C1); C2 = fmaf(q4.z, f4v, C2); C3 = fmaf(q4.w, f4v, C3);
      C0 = fmaf(q5.x, f5v, C0); C1 = fmaf(q5.y, f5v, C1); C2 = fmaf(q5.z, f5v, C2); C3 = fmaf(q5.w, f5v, C3);
      float S0 = q6.x*f6v, S1 = q6.y*f6v, S2 = q6.z*f6v, S3 = q6.w*f6v;
      S0 = fmaf(q7.x, f7v, S0); S1 = fmaf(q7.y, f7v, S1); S2 = fmaf(q7.z, f7v, S2); S3 = fmaf(q7.w, f7v, S3);
      S0 = fmaf(q8.x, f8v, S0); S1 = fmaf(q8.y, f8v, S1); S2 = fmaf(q8.z, f8v, S2); S3 = fmaf(q8.w, f8v, S3);
      S0 = fmaf(q9.x, f9v, S0); S1 = fmaf(q9.y, f9v, S1); S2 = fmaf(q9.z, f9v, S2); S3 = fmaf(q9.w, f9v, S3);
      S0 = fmaf(q10.x, f10v, S0); S1 = fmaf(q10.y, f10v, S1); S2 = fmaf(q10.z, f10v, S2); S3 = fmaf(q10.w, f10v, S3);
      float sp = (fexp2(C0+S0) + fexp2(C1+S1)) + (fexp2(C2+S2) + fexp2(C3+S3));
      float sm = (fexp2(C0-S0) + fexp2(C1-S1)) + (fexp2(C2-S2) + fexp2(C3-S3));
      float hvp = flog2(sp), hvm = flog2(sm);
      smx = fmaxf(smx, fmaxf(hvp, hvm));       // k2 tail lanes: valid duplicates
      if (ok){
        hbuf[ro + a] = (_Float16)hvp;
        if (a) hbuf[ro + 359 - a] = (_Float16)hvm;
      }
      ro += RES_A;
    }
  }
  #pragma unroll
  for (int off = 32; off > 0; off >>= 1)
    smx = fmaxf(smx, __shfl_xor(smx, off, 64));
  if (lane == 0) wred[wave] = smx;
  __syncthreads();
  if (tid == 0){
    float m = fmaxf(fmaxf(wred[0], wred[1]), fmaxf(wred[2], wred[3]));
    atomicMax(gmax + g, enc_f(m));
  }
}

// Fallback (small ws): R16's in-kernel phase-1 + fp32 in-place path.
__global__ __launch_bounds__(256, 4) void compute_fb_kernel(const float* __restrict__ coeffs,
                          const float* __restrict__ PYs, const float* __restrict__ Ftab,
                          float* __restrict__ fbuf, unsigned* __restrict__ gmax){
  int blk   = blockIdx.x;
  int chunk = blk % NCHUNK;
  int gr    = blk / NCHUNK;
  int r = gr % RADII;
  int g = gr / RADII;
  int tid  = threadIdx.x;
  int wave = tid >> 6, lane = tid & 63;
  int b0   = chunk * BCH_BLK;

  __shared__ float cv[CH][IDIM];
  __shared__ __align__(16) float tmpa[BCH_BLK][12][4];
  __shared__ float wred[4];

  for (int v = tid; v < CH*IDIM; v += 256){
    int c = v / IDIM, i = v % IDIM;
    cv[c][i] = coeffs[((g*CH + c)*RADII + r)*IDIM + i];
  }
  float f0[11], f1[11], f2[11];
  {
    const float4* Fq = reinterpret_cast<const float4*>(Ftab);
    float4 a0 = Fq[lane*3],       a1 = Fq[lane*3+1],       a2 = Fq[lane*3+2];
    float4 b0v = Fq[(lane+64)*3], b1 = Fq[(lane+64)*3+1],  b2 = Fq[(lane+64)*3+2];
    float4 c0 = Fq[(lane+128)*3], c1 = Fq[(lane+128)*3+1], c2 = Fq[(lane+128)*3+2];
    f0[0]=a0.x; f0[1]=a0.y; f0[2]=a0.z; f0[3]=a0.w; f0[4]=a1.x; f0[5]=a1.y;
    f0[6]=a1.z; f0[7]=a1.w; f0[8]=a2.x; f0[9]=a2.y; f0[10]=a2.z;
    f1[0]=b0v.x; f1[1]=b0v.y; f1[2]=b0v.z; f1[3]=b0v.w; f1[4]=b1.x; f1[5]=b1.y;
    f1[6]=b1.z; f1[7]=b1.w; f1[8]=b2.x; f1[9]=b2.y; f1[10]=b2.z;
    f2[0]=c0.x; f2[1]=c0.y; f2[2]=c0.z; f2[3]=c0.w; f2[4]=c1.x; f2[5]=c1.y;
    f2[6]=c1.z; f2[7]=c1.w; f2[8]=c2.x; f2[9]=c2.y; f2[10]=c2.z;
  }
  __syncthreads();

  for (int v = tid; v < BCH_BLK*44; v += 256){
    int bl = v / 44, cm = v % 44;
    int c = cm / 11, mm = cm % 11;
    int am, ii;
    if (mm == 0)      { am = 0;      ii = 0;        }
    else if (mm <= 5) { am = mm;     ii = mm;       }
    else              { am = mm - 5; ii = -(mm-5);  }
    const float* py = PYs + (b0 + bl)*36 + am;
    float s = 0.f;
    for (int l = am; l < 6; ++l)
      s = fmaf(cv[c][l*l + l + ii], py[l*6], s);
    tmpa[bl][mm][c] = s;
  }
  __syncthreads();

  float smx[3] = {-1e30f, -1e30f, -1e30f};
  bool tail_ok = (lane < 52);
  size_t rowoff = ((size_t)gr*RES_B + b0 + wave*BCH_W)*RES_A;
  for (int bl = 0; bl < BCH_W; ++bl){
    const float4* tq = reinterpret_cast<const float4*>(&tmpa[wave*BCH_W + bl][0][0]);
    v2f C01[3], C23[3], S01[3], S23[3];
    {
      float4 qv = tq[0];
      v2f a = {qv.x, qv.y}, b = {qv.z, qv.w};
      #pragma unroll
      for (int k = 0; k < 3; ++k){ C01[k] = a; C23[k] = b; }
    }
    #pragma unroll
    for (int mm = 1; mm <= 5; ++mm){
      float4 qv = tq[mm];
      v2f a = {qv.x, qv.y}, b = {qv.z, qv.w};
      C01[0] = __builtin_elementwise_fma(a, (v2f){f0[mm], f0[mm]}, C01[0]);
      C23[0] = __builtin_elementwise_fma(b, (v2f){f0[mm], f0[mm]}, C23[0]);
      C01[1] = __builtin_elementwise_fma(a, (v2f){f1[mm], f1[mm]}, C01[1]);
      C23[1] = __builtin_elementwise_fma(b, (v2f){f1[mm], f1[mm]}, C23[1]);
      C01[2] = __builtin_elementwise_fma(a, (v2f){f2[mm], f2[mm]}, C01[2]);
      C23[2] = __builtin_elementwise_fma(b, (v2f){f2[mm], f2[mm]}, C23[2]);
    }
    {
      float4 qv = tq[6];
      v2f a = {qv.x, qv.y}, b = {qv.z, qv.w};
      S01[0] = a * (v2f){f0[6], f0[6]};  S23[0] = b * (v2f){f0[6], f0[6]};
      S01[1] = a * (v2f){f1[6], f1[6]};  S23[1] = b * (v2f){f1[6], f1[6]};
      S01[2] = a * (v2f){f2[6], f2[6]};  S23[2] = b * (v2f){f2[6], f2[6]};
    }
    #pragma unroll
    for (int mm = 7; mm <= 10; ++mm){
      float4 qv = tq[mm];
      v2f a = {qv.x, qv.y}, b = {qv.z, qv.w};
      S01[0] = __builtin_elementwise_fma(a, (v2f){f0[mm], f0[mm]}, S01[0]);
      S23[0] = __builtin_elementwise_fma(b, (v2f){f0[mm], f0[mm]}, S23[0]);
      S01[1] = __builtin_elementwise_fma(a, (v2f){f1[mm], f1[mm]}, S01[1]);
      S23[1] = __builtin_elementwise_fma(b, (v2f){f1[mm], f1[mm]}, S23[1]);
      S01[2] = __builtin_elementwise_fma(a, (v2f){f2[mm], f2[mm]}, S01[2]);
      S23[2] = __builtin_elementwise_fma(b, (v2f){f2[mm], f2[mm]}, S23[2]);
    }
    #pragma unroll
    for (int k = 0; k < 3; ++k){
      v2f hp0 = C01[k] + S01[k], hp1 = C23[k] + S23[k];
      v2f hm0 = C01[k] - S01[k], hm1 = C23[k] - S23[k];
      float sp = (fexp2(hp0.x) + fexp2(hp0.y)) + (fexp2(hp1.x) + fexp2(hp1.y));
      float sm = (fexp2(hm0.x) + fexp2(hm0.y)) + (fexp2(hm1.x) + fexp2(hm1.y));
      float hvp = flog2(sp), hvm = flog2(sm);
      smx[k] = fmaxf(smx[k], fmaxf(hvp, hvm));
      if (k < 2 || tail_ok){
        int p = lane + 64*k;
        fbuf[rowoff + p] = hvp;
        if (p) fbuf[rowoff + 359 - p] = hvm;
      }
    }
    rowoff += RES_A;
  }
  float smax = fmaxf(fmaxf(smx[0], smx[1]), smx[2]);
  #pragma unroll
  for (int off = 32; off > 0; off >>= 1)
    smax = fmaxf(smax, __shfl_xor(smax, off, 64));
  if (lane == 0) wred[wave] = smax;
  __syncthreads();
  if (tid == 0){
    float m = fmaxf(fmaxf(wred[0], wred[1]), fmaxf(wred[2], wred[3]));
    atomicMax(gmax + g, enc_f(m));
  }
}

template<int HALF>
__global__ __launch_bounds__(256) void fixup_kernel(const _Float16* __restrict__ hbuf,
                                                    float* __restrict__ logits,
                                                    const unsigned* __restrict__ gmax){
  const float LN2 = 0.69314718055994531f;
  if (HALF){
    const int total8 = TOT_L/8;
    const uint4* hv = reinterpret_cast<const uint4*>(hbuf);
    float4* l4 = reinterpret_cast<float4*>(logits);
    int stride = gridDim.x * 256;
    for (int i = blockIdx.x * 256 + threadIdx.x; i < total8; i += stride){
      int g = (int)(((unsigned)i) / (PER_G/8));
      float nsub = -dec_f(gmax[g]) * LN2;
      union { uint4 u; _Float16 h[8]; } un;
      un.u = hv[i];
      float4 o0, o1;
      o0.x = fmaf((float)un.h[0], LN2, nsub);
      o0.y = fmaf((float)un.h[1], LN2, nsub);
      o0.z = fmaf((float)un.h[2], LN2, nsub);
      o0.w = fmaf((float)un.h[3], LN2, nsub);
      o1.x = fmaf((float)un.h[4], LN2, nsub);
      o1.y = fmaf((float)un.h[5], LN2, nsub);
      o1.z = fmaf((float)un.h[6], LN2, nsub);
      o1.w = fmaf((float)un.h[7], LN2, nsub);
      l4[2*i]   = o0;
      l4[2*i+1] = o1;
    }
  } else {
    const int total4 = TOT_L/4;
    float4* l4 = reinterpret_cast<float4*>(logits);
    int stride = gridDim.x * 256;
    for (int i = blockIdx.x * 256 + threadIdx.x; i < total4; i += stride){
      int g = (int)(((unsigned)i) / (PER_G/4));
      float nsub = -dec_f(gmax[g]) * LN2;
      float4 v = l4[i];
      v.x = fmaf(v.x, LN2, nsub); v.y = fmaf(v.y, LN2, nsub);
      v.z = fmaf(v.z, LN2, nsub); v.w = fmaf(v.w, LN2, nsub);
      l4[i] = v;
    }
  }
}

extern "C" void kernel_launch(void* const* d_in, const int* in_sizes, int n_in,
                              void* d_out, int out_size, void* d_ws, size_t ws_size,
                              hipStream_t stream){
  const float* focus = (const float*)d_in[0];
  const float* embt  = (const float*)d_in[1];
  const float* W     = (const float*)d_in[2];
  const int*   tspec = (const int*)d_in[3];
  float* out = (float*)d_out;
  float* ws  = (float*)d_ws;
  unsigned* gmax = (unsigned*)d_ws;          // 32 u32
  float* PYs  = ws + 32;                     // [180][36]
  float* Ftab = ws + 32 + RES_B*36;          // [359][12]
  _Float16* hbuf = (_Float16*)(ws + 16384);  // 83 MB
  float* tmpg = ws + 16384 + TOT_L/2;        // [TMP_T][12][4] = 22.1 MB

  const size_t need = 65536 + (size_t)TOT_L*2 + (size_t)TMP_T*48*4;
  const bool pre = (ws_size >= need);

  hipMemsetAsync(d_ws, 0, 128, stream);
  fused_prep_kernel<<<361, 256, 0, stream>>>(focus, embt, W, tspec, out, PYs, Ftab);
  float* logits = out + COEFF_N;
  if (pre){
    tmp_kernel<<<(TMP_T*11)/256, 256, 0, stream>>>(out, PYs, tmpg);
    compute_sgpr_kernel<<<G_N*RADII*NCHUNK, 256, 0, stream>>>(tmpg, Ftab, hbuf, gmax);
    fixup_kernel<1><<<2048, 256, 0, stream>>>(hbuf, logits, gmax);
  } else {
    compute_fb_kernel<<<G_N*RADII*NCHUNK, 256, 0, stream>>>(out, PYs, Ftab, logits, gmax);
    fixup_kernel<0><<<2048, 256, 0, stream>>>(hbuf, logits, gmax);
  }
}

// Round 19
// 145.327 us; speedup vs baseline: 1.5530x; 1.5530x over previous
//
#include <hip/hip_runtime.h>

#define G_N    32
#define MUL    128
#define RADII  20
#define CH     4
#define RES_B  180
#define RES_A  359
#define IDIM   36
#define COEFF_N (G_N*CH*RADII*IDIM)   // 92160 = 360*256
#define NCHUNK 5
#define BCH_BLK 36                    // betas per block (4 waves)
#define BCH_W   9                     // betas per wave
#define PER_G   (RADII*RES_B*RES_A)   // 1292400
#define TOT_L   (G_N*PER_G)           // 41356800 logits
#define TMP_T   (G_N*RADII*RES_B)     // 115200 rows of [12][4] floats

typedef float v2f __attribute__((ext_vector_type(2)));

__device__ __forceinline__ float fexp2(float x){
#if __has_builtin(__builtin_amdgcn_exp2f)
  return __builtin_amdgcn_exp2f(x);
#else
  return exp2f(x);
#endif
}
__device__ __forceinline__ float flog2(float x){
#if __has_builtin(__builtin_amdgcn_logf)
  return __builtin_amdgcn_logf(x);
#else
  return log2f(x);
#endif
}
__device__ __forceinline__ unsigned enc_f(float f){
  unsigned u = __float_as_uint(f);
  return (u & 0x80000000u) ? ~u : (u | 0x80000000u);
}
__device__ __forceinline__ float dec_f(unsigned k){
  return __uint_as_float((k & 0x80000000u) ? (k ^ 0x80000000u) : ~k);
}

__global__ __launch_bounds__(256) void fused_prep_kernel(
                              const float* __restrict__ focus, const float* __restrict__ embt,
                              const float* __restrict__ W, const int* __restrict__ tspec,
                              float* __restrict__ out,
                              float* __restrict__ PYs, float* __restrict__ Ftab){
  __shared__ double ak[RES_B + 1], bk[RES_B + 1];
  int blk = blockIdx.x;
  int t   = threadIdx.x;
  if (blk == 360){
    const double PI = 3.14159265358979323846;
    const double LOG2E = 1.4426950408889634074;
    if (t >= 2 && t <= RES_B){
      ak[t] = (2.0*t - 1.0) / (double)t;
      bk[t] = (t - 1.0) / (double)t;
    }
    __syncthreads();
    if (t < RES_B){
      int i = RES_B - 1 - t;
      double x = cos(PI * (i + 0.75) / (RES_B + 0.5));
      for (int it = 0; it < 3; ++it){
        double p0 = 1.0, p1 = x;
        for (int k = 2; k <= RES_B; ++k){
          double t1 = ak[k] * x;
          double pk = fma(t1, p1, -(bk[k] * p0));
          p0 = p1; p1 = pk;
        }
        x -= p1 * (x*x - 1.0) / ((double)RES_B * (x*p1 - p0));
      }
      double y = x;
      double sy = sqrt(fmax(1.0 - y*y, 0.0));
      double P[6][6];
      P[0][0] = 1.0;
      for (int m = 1; m < 6; ++m) P[m][m] = (2.0*m - 1.0)*sy*P[m-1][m-1];
      for (int m = 0; m < 5; ++m) P[m+1][m] = (2.0*m + 1.0)*y*P[m][m];
      for (int m = 0; m < 6; ++m)
        for (int l = m + 2; l < 6; ++l)
          P[l][m] = ((2.0*l - 1.0)*y*P[l-1][m] - (l + m - 1.0)*P[l-2][m]) / (double)(l - m);
      const double fact[11] = {1,1,2,6,24,120,720,5040,40320,362880,3628800};
      for (int l = 0; l < 6; ++l)
        for (int m = 0; m <= l; ++m){
          double K = sqrt((2.0*l + 1.0)/(4.0*PI)*fact[l-m]/fact[l+m]);
          double v = K * P[l][m] * LOG2E;
          if (m > 0) v *= sqrt(2.0);
          PYs[t*36 + l*6 + m] = (float)v;
        }
    }
    for (int a = t; a < RES_A; a += 256){
      double al = 2.0*PI*a/(double)RES_A;
      Ftab[a*12 + 0] = 1.0f;
      for (int m = 1; m <= 5; ++m){
        Ftab[a*12 + m]     = (float)cos(m*al);
        Ftab[a*12 + 5 + m] = (float)sin(m*al);
      }
      Ftab[a*12 + 11] = 0.f;
    }
  } else {
    int idx = blk * 256 + t;
    int i36 = idx % IDIM;
    int go  = idx / IDIM;
    int o   = go % (CH*RADII);
    int g   = go / (CH*RADII);
    int l   = (int)sqrtf((float)i36 + 0.5f);
    int mo  = i36 - l*l;
    int dim = 2*l + 1;
    const float* fp = focus + g*(MUL*IDIM) + MUL*l*l + mo;
    const float* ep = embt + tspec[g]*(MUL*6) + MUL*l;
    const float* wp = W + l*(MUL*80) + o;
    float s = 0.f;
    #pragma unroll 4
    for (int i = 0; i < MUL; ++i)
      s = fmaf(fp[i*dim] * ep[i], wp[i*80], s);
    out[idx] = s * 0.088388347648318447f;  // 1/sqrt(128)
  }
}

// Hoisted phase-1: one thread per (t=gr*180+beta, mm), all 4 channels ->
// one coalesced float4 store into the padded [TMP_T][12][4] layout.
__global__ __launch_bounds__(256) void tmp_kernel(const float* __restrict__ coeffs,
                                                  const float* __restrict__ PYs,
                                                  float* __restrict__ tmpg){
  int idx  = blockIdx.x * 256 + threadIdx.x;   // < TMP_T*11 exactly
  int mm   = idx % 11;
  int t    = idx / 11;
  int beta = t % RES_B;
  int gr   = t / RES_B;
  int g = gr / RADII, r = gr % RADII;
  int am, ii;
  if (mm == 0)      { am = 0;      ii = 0;        }
  else if (mm <= 5) { am = mm;     ii = mm;       }
  else              { am = mm - 5; ii = -(mm-5);  }
  const float* py  = PYs + beta*36 + am;
  const float* cvp = coeffs + (size_t)(g*CH*RADII + r)*IDIM;   // channel 0
  float s0 = 0.f, s1 = 0.f, s2 = 0.f, s3 = 0.f;
  for (int l = am; l < 6; ++l){
    float p = py[l*6];
    int o = l*l + l + ii;
    s0 = fmaf(cvp[o],                p, s0);
    s1 = fmaf(cvp[RADII*IDIM + o],   p, s1);
    s2 = fmaf(cvp[2*RADII*IDIM + o], p, s2);
    s3 = fmaf(cvp[3*RADII*IDIM + o], p, s3);
  }
  float4 v = {s0, s1, s2, s3};
  reinterpret_cast<float4*>(tmpg)[t*12 + mm] = v;
}

template<int PRE, int HALF>
__global__ __launch_bounds__(256, 4) void compute_kernel(const float* __restrict__ coeffs,
                          const float* __restrict__ PYs, const float* __restrict__ Ftab,
                          const float* __restrict__ tmpg,
                          _Float16* __restrict__ hbuf, float* __restrict__ fbuf,
                          unsigned* __restrict__ gmax){
  int blk   = blockIdx.x;
  int chunk = blk % NCHUNK;
  int gr    = blk / NCHUNK;
  int r = gr % RADII;
  int g = gr / RADII;
  int tid  = threadIdx.x;
  int wave = tid >> 6, lane = tid & 63;
  int b0   = chunk * BCH_BLK;

  __shared__ float cv[CH][IDIM];
  __shared__ __align__(16) float tmpa[BCH_BLK][12][4];
  __shared__ float wred[4];

  if (PRE){
    const float4* src = reinterpret_cast<const float4*>(tmpg) + ((size_t)gr*RES_B + b0)*12;
    float4* dst = reinterpret_cast<float4*>(&tmpa[0][0][0]);
    dst[tid] = src[tid];                           // 0..255
    if (tid < 176) dst[256 + tid] = src[256 + tid];// 256..431 (36*12 = 432)
  } else {
    for (int v = tid; v < CH*IDIM; v += 256){
      int c = v / IDIM, i = v % IDIM;
      cv[c][i] = coeffs[((g*CH + c)*RADII + r)*IDIM + i];
    }
  }
  float f0[11], f1[11], f2[11];
  {
    const float4* Fq = reinterpret_cast<const float4*>(Ftab);
    float4 a0 = Fq[lane*3],       a1 = Fq[lane*3+1],       a2 = Fq[lane*3+2];
    float4 b0v = Fq[(lane+64)*3], b1 = Fq[(lane+64)*3+1],  b2 = Fq[(lane+64)*3+2];
    float4 c0 = Fq[(lane+128)*3], c1 = Fq[(lane+128)*3+1], c2 = Fq[(lane+128)*3+2];
    f0[0]=a0.x; f0[1]=a0.y; f0[2]=a0.z; f0[3]=a0.w; f0[4]=a1.x; f0[5]=a1.y;
    f0[6]=a1.z; f0[7]=a1.w; f0[8]=a2.x; f0[9]=a2.y; f0[10]=a2.z;
    f1[0]=b0v.x; f1[1]=b0v.y; f1[2]=b0v.z; f1[3]=b0v.w; f1[4]=b1.x; f1[5]=b1.y;
    f1[6]=b1.z; f1[7]=b1.w; f1[8]=b2.x; f1[9]=b2.y; f1[10]=b2.z;
    f2[0]=c0.x; f2[1]=c0.y; f2[2]=c0.z; f2[3]=c0.w; f2[4]=c1.x; f2[5]=c1.y;
    f2[6]=c1.z; f2[7]=c1.w; f2[8]=c2.x; f2[9]=c2.y; f2[10]=c2.z;
  }
  __syncthreads();

  if (!PRE){
    for (int v = tid; v < BCH_BLK*44; v += 256){
      int bl = v / 44, cm = v % 44;
      int c = cm / 11, mm = cm % 11;
      int am, ii;
      if (mm == 0)      { am = 0;      ii = 0;        }
      else if (mm <= 5) { am = mm;     ii = mm;       }
      else              { am = mm - 5; ii = -(mm-5);  }
      const float* py = PYs + (b0 + bl)*36 + am;
      float s = 0.f;
      for (int l = am; l < 6; ++l)
        s = fmaf(cv[c][l*l + l + ii], py[l*6], s);
      tmpa[bl][mm][c] = s;
    }
    __syncthreads();
  }

  float smx[3] = {-1e30f, -1e30f, -1e30f};
  bool tail_ok = (lane < 52);
  size_t rowoff = ((size_t)gr*RES_B + b0 + wave*BCH_W)*RES_A;
  for (int bl = 0; bl < BCH_W; ++bl){
    const float4* tq = reinterpret_cast<const float4*>(&tmpa[wave*BCH_W + bl][0][0]);
    v2f C01[3], C23[3], S01[3], S23[3];
    {
      float4 qv = tq[0];
      v2f a = {qv.x, qv.y}, b = {qv.z, qv.w};
      #pragma unroll
      for (int k = 0; k < 3; ++k){ C01[k] = a; C23[k] = b; }
    }
    #pragma unroll
    for (int mm = 1; mm <= 5; ++mm){
      float4 qv = tq[mm];
      v2f a = {qv.x, qv.y}, b = {qv.z, qv.w};
      C01[0] = __builtin_elementwise_fma(a, (v2f){f0[mm], f0[mm]}, C01[0]);
      C23[0] = __builtin_elementwise_fma(b, (v2f){f0[mm], f0[mm]}, C23[0]);
      C01[1] = __builtin_elementwise_fma(a, (v2f){f1[mm], f1[mm]}, C01[1]);
      C23[1] = __builtin_elementwise_fma(b, (v2f){f1[mm], f1[mm]}, C23[1]);
      C01[2] = __builtin_elementwise_fma(a, (v2f){f2[mm], f2[mm]}, C01[2]);
      C23[2] = __builtin_elementwise_fma(b, (v2f){f2[mm], f2[mm]}, C23[2]);
    }
    {
      float4 qv = tq[6];
      v2f a = {qv.x, qv.y}, b = {qv.z, qv.w};
      S01[0] = a * (v2f){f0[6], f0[6]};  S23[0] = b * (v2f){f0[6], f0[6]};
      S01[1] = a * (v2f){f1[6], f1[6]};  S23[1] = b * (v2f){f1[6], f1[6]};
      S01[2] = a * (v2f){f2[6], f2[6]};  S23[2] = b * (v2f){f2[6], f2[6]};
    }
    #pragma unroll
    for (int mm = 7; mm <= 10; ++mm){
      float4 qv = tq[mm];
      v2f a = {qv.x, qv.y}, b = {qv.z, qv.w};
      S01[0] = __builtin_elementwise_fma(a, (v2f){f0[mm], f0[mm]}, S01[0]);
      S23[0] = __builtin_elementwise_fma(b, (v2f){f0[mm], f0[mm]}, S23[0]);
      S01[1] = __builtin_elementwise_fma(a, (v2f){f1[mm], f1[mm]}, S01[1]);
      S23[1] = __builtin_elementwise_fma(b, (v2f){f1[mm], f1[mm]}, S23[1]);
      S01[2] = __builtin_elementwise_fma(a, (v2f){f2[mm], f2[mm]}, S01[2]);
      S23[2] = __builtin_elementwise_fma(b, (v2f){f2[mm], f2[mm]}, S23[2]);
    }
    #pragma unroll
    for (int k = 0; k < 3; ++k){
      v2f hp0 = C01[k] + S01[k], hp1 = C23[k] + S23[k];
      v2f hm0 = C01[k] - S01[k], hm1 = C23[k] - S23[k];
      float sp = (fexp2(hp0.x) + fexp2(hp0.y)) + (fexp2(hp1.x) + fexp2(hp1.y));
      float sm = (fexp2(hm0.x) + fexp2(hm0.y)) + (fexp2(hm1.x) + fexp2(hm1.y));
      float hvp = flog2(sp), hvm = flog2(sm);
      smx[k] = fmaxf(smx[k], fmaxf(hvp, hvm));
      if (k < 2 || tail_ok){
        int p = lane + 64*k;
        if (HALF){
          hbuf[rowoff + p] = (_Float16)hvp;
          if (p) hbuf[rowoff + 359 - p] = (_Float16)hvm;
        } else {
          fbuf[rowoff + p] = hvp;
          if (p) fbuf[rowoff + 359 - p] = hvm;
        }
      }
    }
    rowoff += RES_A;
  }
  float smax = fmaxf(fmaxf(smx[0], smx[1]), smx[2]);
  #pragma unroll
  for (int off = 32; off > 0; off >>= 1)
    smax = fmaxf(smax, __shfl_xor(smax, off, 64));
  if (lane == 0) wred[wave] = smax;
  __syncthreads();
  if (tid == 0){
    float m = fmaxf(fmaxf(wred[0], wred[1]), fmaxf(wred[2], wred[3]));
    atomicMax(gmax + g, enc_f(m));
  }
}

template<int HALF>
__global__ __launch_bounds__(256) void fixup_kernel(const _Float16* __restrict__ hbuf,
                                                    float* __restrict__ logits,
                                                    const unsigned* __restrict__ gmax){
  const float LN2 = 0.69314718055994531f;
  if (HALF){
    const int total8 = TOT_L/8;
    const uint4* hv = reinterpret_cast<const uint4*>(hbuf);
    float4* l4 = reinterpret_cast<float4*>(logits);
    int stride = gridDim.x * 256;
    for (int i = blockIdx.x * 256 + threadIdx.x; i < total8; i += stride){
      int g = (int)(((unsigned)i) / (PER_G/8));
      float nsub = -dec_f(gmax[g]) * LN2;
      union { uint4 u; _Float16 h[8]; } un;
      un.u = hv[i];
      float4 o0, o1;
      o0.x = fmaf((float)un.h[0], LN2, nsub);
      o0.y = fmaf((float)un.h[1], LN2, nsub);
      o0.z = fmaf((float)un.h[2], LN2, nsub);
      o0.w = fmaf((float)un.h[3], LN2, nsub);
      o1.x = fmaf((float)un.h[4], LN2, nsub);
      o1.y = fmaf((float)un.h[5], LN2, nsub);
      o1.z = fmaf((float)un.h[6], LN2, nsub);
      o1.w = fmaf((float)un.h[7], LN2, nsub);
      l4[2*i]   = o0;
      l4[2*i+1] = o1;
    }
  } else {
    const int total4 = TOT_L/4;
    float4* l4 = reinterpret_cast<float4*>(logits);
    int stride = gridDim.x * 256;
    for (int i = blockIdx.x * 256 + threadIdx.x; i < total4; i += stride){
      int g = (int)(((unsigned)i) / (PER_G/4));
      float nsub = -dec_f(gmax[g]) * LN2;
      float4 v = l4[i];
      v.x = fmaf(v.x, LN2, nsub); v.y = fmaf(v.y, LN2, nsub);
      v.z = fmaf(v.z, LN2, nsub); v.w = fmaf(v.w, LN2, nsub);
      l4[i] = v;
    }
  }
}

extern "C" void kernel_launch(void* const* d_in, const int* in_sizes, int n_in,
                              void* d_out, int out_size, void* d_ws, size_t ws_size,
                              hipStream_t stream){
  const float* focus = (const float*)d_in[0];
  const float* embt  = (const float*)d_in[1];
  const float* W     = (const float*)d_in[2];
  const int*   tspec = (const int*)d_in[3];
  float* out = (float*)d_out;
  float* ws  = (float*)d_ws;
  unsigned* gmax = (unsigned*)d_ws;          // 32 u32
  float* PYs  = ws + 32;                     // [180][36]
  float* Ftab = ws + 32 + RES_B*36;          // [359][12]
  _Float16* hbuf = (_Float16*)(ws + 16384);  // 83 MB
  float* tmpg = ws + 16384 + TOT_L/2;        // [TMP_T][12][4] = 22.1 MB

  const size_t need = 65536 + (size_t)TOT_L*2 + (size_t)TMP_T*48*4;
  const bool pre = (ws_size >= need);

  hipMemsetAsync(d_ws, 0, 128, stream);
  fused_prep_kernel<<<361, 256, 0, stream>>>(focus, embt, W, tspec, out, PYs, Ftab);
  float* logits = out + COEFF_N;
  if (pre){
    tmp_kernel<<<(TMP_T*11)/256, 256, 0, stream>>>(out, PYs, tmpg);
    compute_kernel<1,1><<<G_N*RADII*NCHUNK, 256, 0, stream>>>(out, PYs, Ftab, tmpg, hbuf, logits, gmax);
    fixup_kernel<1><<<2048, 256, 0, stream>>>(hbuf, logits, gmax);
  } else {
    compute_kernel<0,0><<<G_N*RADII*NCHUNK, 256, 0, stream>>>(out, PYs, Ftab, tmpg, hbuf, logits, gmax);
    fixup_kernel<0><<<2048, 256, 0, stream>>>(hbuf, logits, gmax);
  }
}